// Round 4
// baseline (170.118 us; speedup 1.0000x reference)
//
#include <hip/hip_runtime.h>

#define BB 4
#define CCH 256
#define OCH 256
#define HH 64
#define WW 64
#define HWSZ 4096

typedef __bf16 bf16_t;
typedef bf16_t bf16x8 __attribute__((ext_vector_type(8)));
typedef float f32x4 __attribute__((ext_vector_type(4)));

__device__ __forceinline__ unsigned int bpack(float a, float b) {
    unsigned int ua = __float_as_uint(a);
    ua = (ua + 0x7FFFu + ((ua >> 16) & 1u)) >> 16;
    unsigned int ub = __float_as_uint(b);
    ub = (ub + 0x7FFFu + ((ub >> 16) & 1u)) >> 16;
    return ua | (ub << 16);
}

// ---------------------------------------------------------------------------
// Kernel 1a: w_off [27][C][9] -> w1F bf16 frag-major [9 k][32 cSub][32 o][8 j]
// ---------------------------------------------------------------------------
__global__ void k_w1f(const float* __restrict__ w_off, ushort* __restrict__ w1F) {
    int i = blockIdx.x * blockDim.x + threadIdx.x;
    if (i >= 9 * 32 * 32 * 8) return;
    int j = i & 7;
    int o = (i >> 3) & 31;
    int cSub = (i >> 8) & 31;
    int k = i >> 13;
    float v = 0.0f;
    if (o < 27) v = w_off[((size_t)o * CCH + cSub * 8 + j) * 9 + k];
    unsigned int u = __float_as_uint(v);
    u = (u + 0x7FFFu + ((u >> 16) & 1u)) >> 16;
    w1F[i] = (ushort)u;
}

// ---------------------------------------------------------------------------
// Kernel 1b: w_def [O][C][9] -> w2F bf16 frag-major [9 k][32 cg][256 o][8 j]
// ---------------------------------------------------------------------------
__global__ void k_w2f(const float* __restrict__ w_def, ushort* __restrict__ w2F) {
    int i = blockIdx.x * blockDim.x + threadIdx.x;
    if (i >= 9 * 32 * 256 * 8) return;
    int j = i & 7;
    int o = (i >> 3) & 255;
    int cg = (i >> 11) & 31;
    int k = i >> 16;
    int c = cg * 8 + j;
    float v = w_def[(size_t)o * 2304 + c * 9 + k];
    unsigned int u = __float_as_uint(v);
    u = (u + 0x7FFFu + ((u >> 16) & 1u)) >> 16;
    w2F[i] = (ushort)u;
}

// ---------------------------------------------------------------------------
// Kernel 2: pred conv via MFMA (atomic K-split x4). grid = 1024.
// ---------------------------------------------------------------------------
__global__ __launch_bounds__(256) void k_pred2(const float* __restrict__ x,
                                               const ushort* __restrict__ w1F,
                                               float* __restrict__ P) {
    int blk = blockIdx.x;
    int g = blk & 3;
    int h = (blk >> 2) & 63;
    int b = blk >> 8;
    int tid = threadIdx.x;
    int spx  = tid & 63;
    int sgrp = tid >> 6;
    int lane = tid & 63;
    int wv   = tid >> 6;
    int l16  = lane & 15;
    int lq   = lane >> 4;

    __shared__ ushort b_lds[2][4][4][16][8];

    const float* xb = x + (size_t)b * CCH * HWSZ;
    const bf16x8* w1v = (const bf16x8*)w1F;

    f32x4 acc[2];
    acc[0] = (f32x4){0.f, 0.f, 0.f, 0.f};
    acc[1] = (f32x4){0.f, 0.f, 0.f, 0.f};

    auto stage = [&](int t, int buf) {
        int cg = 2 * g + (t >= 9);
        int k = t - (t >= 9 ? 9 : 0);
        int y   = h + k / 3 - 1;
        int pxs = spx + k % 3 - 1;
        bool ok = (y >= 0 && y < HH && pxs >= 0 && pxs < WW);
        const float* xp = xb + (size_t)(cg * 32 + sgrp * 8) * HWSZ + y * WW + pxs;
        float v[8];
#pragma unroll
        for (int j = 0; j < 8; ++j) v[j] = ok ? xp[(size_t)j * HWSZ] : 0.0f;
        uint4 d;
        d.x = bpack(v[0], v[1]);
        d.y = bpack(v[2], v[3]);
        d.z = bpack(v[4], v[5]);
        d.w = bpack(v[6], v[7]);
        *(uint4*)&b_lds[buf][sgrp][spx >> 4][spx & 15][0] = d;
    };

    stage(0, 0);
    __syncthreads();

    for (int t = 0; t < 18; ++t) {
        int cur = t & 1;
        int cg = 2 * g + (t >= 9);
        int k  = t - (t >= 9 ? 9 : 0);
        int row = k * 32 + cg * 4 + lq;
        bf16x8 a0 = w1v[(size_t)row * 32 + 0 * 16 + l16];
        bf16x8 a1 = w1v[(size_t)row * 32 + 1 * 16 + l16];
        if (t < 17) stage(t + 1, cur ^ 1);
        bf16x8 bfrag = *(const bf16x8*)&b_lds[cur][lq][wv][l16][0];
        acc[0] = __builtin_amdgcn_mfma_f32_16x16x32_bf16(a0, bfrag, acc[0], 0, 0, 0);
        acc[1] = __builtin_amdgcn_mfma_f32_16x16x32_bf16(a1, bfrag, acc[1], 0, 0, 0);
        __syncthreads();
    }

#pragma unroll
    for (int mf = 0; mf < 2; ++mf) {
#pragma unroll
        for (int r = 0; r < 4; ++r) {
            int o = mf * 16 + lq * 4 + r;
            if (o < 27) {
                atomicAdd(&P[((size_t)b * 27 + o) * HWSZ + h * WW + wv * 16 + l16],
                          acc[mf][r]);
            }
        }
    }
}

// ---------------------------------------------------------------------------
// Kernel 2b: finalize P in place: + bias, sigmoid on mask planes
// ---------------------------------------------------------------------------
__global__ void k_pfin(float* __restrict__ P, const float* __restrict__ b_off) {
    int i = blockIdx.x * blockDim.x + threadIdx.x;
    if (i >= BB * 27 * HWSZ) return;
    int j = (i >> 12) % 27;
    float v = P[i] + b_off[j];
    if (j >= 18) v = 1.0f / (1.0f + expf(-v));
    P[i] = v;
}

// ---------------------------------------------------------------------------
// Kernel 2c: prefill out with bias (float4)
// ---------------------------------------------------------------------------
__global__ void k_ofill(float* __restrict__ out, const float* __restrict__ b_def) {
    int i = blockIdx.x * blockDim.x + threadIdx.x;
    if (i >= BB * OCH * HWSZ / 4) return;
    float v = b_def[(i >> 10) & 255];
    ((float4*)out)[i] = make_float4(v, v, v, v);
}

// ---------------------------------------------------------------------------
// Kernel 3: deformable sampling + bf16 MFMA GEMM. 2-way K-split, atomic out.
// grid = 1024. XCD-swizzled: L = (bid&7)*128 + bid>>3;
// L -> ks = L&1, half = (L>>1)&1, h = (L>>2)&63, b = L>>8.
// Each XCD owns one b and a contiguous 32-row h band (x slice ~2.5MB, L2-fit).
// ---------------------------------------------------------------------------
__global__ __launch_bounds__(256) void k_deform3(const float* __restrict__ x,
                                                 const float* __restrict__ P,
                                                 const ushort* __restrict__ w2F,
                                                 float* __restrict__ out) {
    int bid = blockIdx.x;
    int L = (bid & 7) * 128 + (bid >> 3);
    int ks   = L & 1;
    int px0  = ((L >> 1) & 1) * 32;
    int h    = (L >> 2) & 63;
    int b    = L >> 8;
    int tid = threadIdx.x;
    int spx  = tid & 31;
    int sgrp = tid >> 5;
    int pxg  = px0 + spx;
    int lane = tid & 63;
    int wm   = tid >> 6;
    int l16  = lane & 15;
    int lq   = lane >> 4;

    __shared__ ushort b_lds[2][4][2][16][8];

    const float* xb = x + (size_t)b * CCH * HWSZ;
    const bf16x8* w2v = (const bf16x8*)w2F;

    f32x4 acc[4][2];
#pragma unroll
    for (int mf = 0; mf < 4; ++mf)
#pragma unroll
        for (int nf = 0; nf < 2; ++nf) acc[mf][nf] = (f32x4){0.f, 0.f, 0.f, 0.f};

    float wgt[4];
    int aoff[4];
    const float* Pb = P + (size_t)b * 27 * HWSZ + h * WW + pxg;

    auto make_desc = [&](int k) {
        float offy = Pb[(size_t)(2 * k) * HWSZ];
        float offx = Pb[(size_t)(2 * k + 1) * HWSZ];
        float m    = Pb[(size_t)(18 + k) * HWSZ];
        float sy = offy + (float)(h + k / 3 - 1);
        float sx = offx + (float)(pxg + k % 3 - 1);
        float y0f = floorf(sy), x0f = floorf(sx);
        float ty = sy - y0f, tx = sx - x0f;
        int y0 = (int)y0f, x0 = (int)x0f;
#pragma unroll
        for (int dy = 0; dy < 2; ++dy) {
#pragma unroll
            for (int dx = 0; dx < 2; ++dx) {
                int yi = y0 + dy, xi = x0 + dx;
                bool ok = (yi >= 0 && yi < HH && xi >= 0 && xi < WW);
                float wg = (dy ? ty : 1.0f - ty) * (dx ? tx : 1.0f - tx) * m;
                wgt[dy * 2 + dx]  = ok ? wg : 0.0f;
                aoff[dy * 2 + dx] = ok ? (yi * WW + xi) : 0;
            }
        }
    };

    const int t0 = ks * 36;
    const int t1 = t0 + 36;

    make_desc(t0 >> 3);
    // prologue: stage chunk t0 into buf 0
    {
        const float* xp = xb + (size_t)((t0 & 7) * 32 + sgrp * 4) * HWSZ;
        float g[4][4];
#pragma unroll
        for (int i = 0; i < 4; ++i)
#pragma unroll
            for (int j = 0; j < 4; ++j) g[i][j] = xp[(size_t)i * HWSZ + aoff[j]];
        float v[4];
#pragma unroll
        for (int i = 0; i < 4; ++i)
            v[i] = g[i][0] * wgt[0] + g[i][1] * wgt[1] + g[i][2] * wgt[2] + g[i][3] * wgt[3];
        unsigned int* dst = (unsigned int*)&b_lds[0][sgrp >> 1][spx >> 4][spx & 15][(sgrp & 1) * 4];
        dst[0] = bpack(v[0], v[1]);
        dst[1] = bpack(v[2], v[3]);
    }
    bf16x8 aCur[4];
    {
        int row = (t0 >> 3) * 32 + (t0 & 7) * 4 + lq;
#pragma unroll
        for (int mf = 0; mf < 4; ++mf)
            aCur[mf] = w2v[(size_t)row * 256 + wm * 64 + mf * 16 + l16];
    }
    __syncthreads();

#pragma unroll 2
    for (int t = t0; t < t1; ++t) {
        int cur = (t - t0) & 1;
        bool pf = (t < t1 - 1);
        bf16x8 aNxt[4];
        float g[4][4];
        if (pf) {
            int tn = t + 1;
            int kn = tn >> 3;
            int row = kn * 32 + (tn & 7) * 4 + lq;
#pragma unroll
            for (int mf = 0; mf < 4; ++mf)
                aNxt[mf] = w2v[(size_t)row * 256 + wm * 64 + mf * 16 + l16];
            if ((tn & 7) == 0) make_desc(kn);
            const float* xp = xb + (size_t)((tn & 7) * 32 + sgrp * 4) * HWSZ;
#pragma unroll
            for (int i = 0; i < 4; ++i)
#pragma unroll
                for (int j = 0; j < 4; ++j) g[i][j] = xp[(size_t)i * HWSZ + aoff[j]];
        }
        bf16x8 b0 = *(const bf16x8*)&b_lds[cur][lq][0][l16][0];
        bf16x8 b1 = *(const bf16x8*)&b_lds[cur][lq][1][l16][0];
#pragma unroll
        for (int mf = 0; mf < 4; ++mf) {
            acc[mf][0] = __builtin_amdgcn_mfma_f32_16x16x32_bf16(aCur[mf], b0, acc[mf][0], 0, 0, 0);
            acc[mf][1] = __builtin_amdgcn_mfma_f32_16x16x32_bf16(aCur[mf], b1, acc[mf][1], 0, 0, 0);
        }
        if (pf) {
            float v[4];
#pragma unroll
            for (int i = 0; i < 4; ++i)
                v[i] = g[i][0] * wgt[0] + g[i][1] * wgt[1] + g[i][2] * wgt[2] + g[i][3] * wgt[3];
            unsigned int* dst = (unsigned int*)&b_lds[cur ^ 1][sgrp >> 1][spx >> 4][spx & 15][(sgrp & 1) * 4];
            dst[0] = bpack(v[0], v[1]);
            dst[1] = bpack(v[2], v[3]);
        }
        __syncthreads();
        if (pf) {
#pragma unroll
            for (int mf = 0; mf < 4; ++mf) aCur[mf] = aNxt[mf];
        }
    }

    // epilogue: atomic accumulate (out prefilled with bias)
#pragma unroll
    for (int mf = 0; mf < 4; ++mf) {
#pragma unroll
        for (int nf = 0; nf < 2; ++nf) {
#pragma unroll
            for (int r = 0; r < 4; ++r) {
                int o = wm * 64 + mf * 16 + lq * 4 + r;
                atomicAdd(&out[((size_t)b * OCH + o) * HWSZ + h * WW + px0 + nf * 16 + l16],
                          acc[mf][nf][r]);
            }
        }
    }
}

// ---------------------------------------------------------------------------
extern "C" void kernel_launch(void* const* d_in, const int* in_sizes, int n_in,
                              void* d_out, int out_size, void* d_ws, size_t ws_size,
                              hipStream_t stream) {
    const float* x     = (const float*)d_in[0];
    const float* w_off = (const float*)d_in[1];
    const float* b_off = (const float*)d_in[2];
    const float* w_def = (const float*)d_in[3];
    const float* b_def = (const float*)d_in[4];
    float* out = (float*)d_out;

    float*  P   = (float*)d_ws;                            // 442368 floats
    ushort* w1F = (ushort*)(P + (size_t)BB * 27 * HWSZ);   // 73728 bf16
    ushort* w2F = w1F + 73728;                             // 589824 bf16

    hipMemsetAsync(P, 0, (size_t)BB * 27 * HWSZ * sizeof(float), stream);
    hipLaunchKernelGGL(k_w1f, dim3(288), dim3(256), 0, stream, w_off, w1F);
    hipLaunchKernelGGL(k_w2f, dim3(2304), dim3(256), 0, stream, w_def, w2F);
    hipLaunchKernelGGL(k_pred2, dim3(1024), dim3(256), 0, stream, x, w1F, P);
    hipLaunchKernelGGL(k_pfin, dim3(1728), dim3(256), 0, stream, P, b_off);
    hipLaunchKernelGGL(k_ofill, dim3(4096), dim3(256), 0, stream, out, b_def);
    hipLaunchKernelGGL(k_deform3, dim3(1024), dim3(256), 0, stream, x, P, w2F, out);
}

// Round 5
// 114.213 us; speedup vs baseline: 1.4895x; 1.4895x over previous
//
#include <hip/hip_runtime.h>

#define BB 4
#define CCH 256
#define OCH 256
#define HH 64
#define WW 64
#define HWSZ 4096

typedef __bf16 bf16_t;
typedef bf16_t bf16x8 __attribute__((ext_vector_type(8)));
typedef float f32x4 __attribute__((ext_vector_type(4)));

__device__ __forceinline__ unsigned int bpack(float a, float b) {
    unsigned int ua = __float_as_uint(a);
    ua = (ua + 0x7FFFu + ((ua >> 16) & 1u)) >> 16;
    unsigned int ub = __float_as_uint(b);
    ub = (ub + 0x7FFFu + ((ub >> 16) & 1u)) >> 16;
    return ua | (ub << 16);
}
__device__ __forceinline__ float blo(unsigned int u) { return __uint_as_float(u << 16); }
__device__ __forceinline__ float bhi(unsigned int u) { return __uint_as_float(u & 0xFFFF0000u); }

// ---------------------------------------------------------------------------
// Kernel 0: transpose x [B][C][H][W] f32 -> xT [B][H][W][C] bf16
// grid = B*H. LDS u32[64 w][130 c2] (pad 130 -> 2-way banks, free).
// ---------------------------------------------------------------------------
__global__ __launch_bounds__(256) void k_xT(const float* __restrict__ x,
                                            ushort* __restrict__ xT) {
    int b = blockIdx.x >> 6;
    int h = blockIdx.x & 63;
    int tid = threadIdx.x;
    int wv = tid >> 6;
    int lane = tid & 63;

    __shared__ unsigned int buf[64][130];

    const float* xp = x + ((size_t)b * CCH + wv * 64) * HWSZ + h * WW + lane;
#pragma unroll 8
    for (int i = 0; i < 32; ++i) {
        float a = xp[(size_t)(2 * i) * HWSZ];
        float c = xp[(size_t)(2 * i + 1) * HWSZ];
        buf[lane][wv * 32 + i] = bpack(a, c);
    }
    __syncthreads();

    ushort* dst = xT + ((size_t)(b * 64 + h) * 64) * 256;
#pragma unroll
    for (int r = 0; r < 16; ++r) {
        int idx = tid + r * 256;          // 0..4095
        int w = idx >> 6;
        int q = idx & 63;                 // u64 slot: channels 4q..4q+3
        uint2 v = *(const uint2*)&buf[w][2 * q];
        *(uint2*)(dst + (size_t)w * 256 + q * 4) = v;
    }
}

// ---------------------------------------------------------------------------
// Kernel 1a: w_off [27][C][9] -> w1F bf16 frag-major [9 k][32 cSub][32 o][8 j]
// ---------------------------------------------------------------------------
__global__ void k_w1f(const float* __restrict__ w_off, ushort* __restrict__ w1F) {
    int i = blockIdx.x * blockDim.x + threadIdx.x;
    if (i >= 9 * 32 * 32 * 8) return;
    int j = i & 7;
    int o = (i >> 3) & 31;
    int cSub = (i >> 8) & 31;
    int k = i >> 13;
    float v = 0.0f;
    if (o < 27) v = w_off[((size_t)o * CCH + cSub * 8 + j) * 9 + k];
    unsigned int u = __float_as_uint(v);
    u = (u + 0x7FFFu + ((u >> 16) & 1u)) >> 16;
    w1F[i] = (ushort)u;
}

// ---------------------------------------------------------------------------
// Kernel 1b: w_def [O][C][9] -> w2F bf16 frag-major [9 k][32 cg][256 o][8 j]
// ---------------------------------------------------------------------------
__global__ void k_w2f(const float* __restrict__ w_def, ushort* __restrict__ w2F) {
    int i = blockIdx.x * blockDim.x + threadIdx.x;
    if (i >= 9 * 32 * 256 * 8) return;
    int j = i & 7;
    int o = (i >> 3) & 255;
    int cg = (i >> 11) & 31;
    int k = i >> 16;
    int c = cg * 8 + j;
    float v = w_def[(size_t)o * 2304 + c * 9 + k];
    unsigned int u = __float_as_uint(v);
    u = (u + 0x7FFFu + ((u >> 16) & 1u)) >> 16;
    w2F[i] = (ushort)u;
}

// ---------------------------------------------------------------------------
// Kernel 2: pred conv via MFMA (atomic K-split x4). grid = 1024.
// ---------------------------------------------------------------------------
__global__ __launch_bounds__(256) void k_pred2(const float* __restrict__ x,
                                               const ushort* __restrict__ w1F,
                                               float* __restrict__ P) {
    int blk = blockIdx.x;
    int g = blk & 3;
    int h = (blk >> 2) & 63;
    int b = blk >> 8;
    int tid = threadIdx.x;
    int spx  = tid & 63;
    int sgrp = tid >> 6;
    int lane = tid & 63;
    int wv   = tid >> 6;
    int l16  = lane & 15;
    int lq   = lane >> 4;

    __shared__ ushort b_lds[2][4][4][16][8];

    const float* xb = x + (size_t)b * CCH * HWSZ;
    const bf16x8* w1v = (const bf16x8*)w1F;

    f32x4 acc[2];
    acc[0] = (f32x4){0.f, 0.f, 0.f, 0.f};
    acc[1] = (f32x4){0.f, 0.f, 0.f, 0.f};

    auto stage = [&](int t, int buf) {
        int cg = 2 * g + (t >= 9);
        int k = t - (t >= 9 ? 9 : 0);
        int y   = h + k / 3 - 1;
        int pxs = spx + k % 3 - 1;
        bool ok = (y >= 0 && y < HH && pxs >= 0 && pxs < WW);
        const float* xp = xb + (size_t)(cg * 32 + sgrp * 8) * HWSZ + y * WW + pxs;
        float v[8];
#pragma unroll
        for (int j = 0; j < 8; ++j) v[j] = ok ? xp[(size_t)j * HWSZ] : 0.0f;
        uint4 d;
        d.x = bpack(v[0], v[1]);
        d.y = bpack(v[2], v[3]);
        d.z = bpack(v[4], v[5]);
        d.w = bpack(v[6], v[7]);
        *(uint4*)&b_lds[buf][sgrp][spx >> 4][spx & 15][0] = d;
    };

    stage(0, 0);
    __syncthreads();

    for (int t = 0; t < 18; ++t) {
        int cur = t & 1;
        int cg = 2 * g + (t >= 9);
        int k  = t - (t >= 9 ? 9 : 0);
        int row = k * 32 + cg * 4 + lq;
        bf16x8 a0 = w1v[(size_t)row * 32 + 0 * 16 + l16];
        bf16x8 a1 = w1v[(size_t)row * 32 + 1 * 16 + l16];
        if (t < 17) stage(t + 1, cur ^ 1);
        bf16x8 bfrag = *(const bf16x8*)&b_lds[cur][lq][wv][l16][0];
        acc[0] = __builtin_amdgcn_mfma_f32_16x16x32_bf16(a0, bfrag, acc[0], 0, 0, 0);
        acc[1] = __builtin_amdgcn_mfma_f32_16x16x32_bf16(a1, bfrag, acc[1], 0, 0, 0);
        __syncthreads();
    }

#pragma unroll
    for (int mf = 0; mf < 2; ++mf) {
#pragma unroll
        for (int r = 0; r < 4; ++r) {
            int o = mf * 16 + lq * 4 + r;
            if (o < 27) {
                atomicAdd(&P[((size_t)b * 27 + o) * HWSZ + h * WW + wv * 16 + l16],
                          acc[mf][r]);
            }
        }
    }
}

// ---------------------------------------------------------------------------
// Kernel 2b: finalize P in place: + bias, sigmoid on mask planes
// ---------------------------------------------------------------------------
__global__ void k_pfin(float* __restrict__ P, const float* __restrict__ b_off) {
    int i = blockIdx.x * blockDim.x + threadIdx.x;
    if (i >= BB * 27 * HWSZ) return;
    int j = (i >> 12) % 27;
    float v = P[i] + b_off[j];
    if (j >= 18) v = 1.0f / (1.0f + expf(-v));
    P[i] = v;
}

// ---------------------------------------------------------------------------
// Kernel 2c: prefill out with bias (float4)
// ---------------------------------------------------------------------------
__global__ void k_ofill(float* __restrict__ out, const float* __restrict__ b_def) {
    int i = blockIdx.x * blockDim.x + threadIdx.x;
    if (i >= BB * OCH * HWSZ / 4) return;
    float v = b_def[(i >> 10) & 255];
    ((float4*)out)[i] = make_float4(v, v, v, v);
}

// ---------------------------------------------------------------------------
// Kernel 3: deformable sampling from xT (channel-dense) + bf16 MFMA GEMM.
// grid = 1024, XCD-swizzled: L = (bid&7)*128 + bid>>3;
// L -> cs = L&1 (channel half), px half, h, b. 2-way C-split, atomic out.
// Chunk t (0..35): k = t>>2, cgl = t&3 -> channels cs*128 + cgl*32 + [0,32).
// Gather: lane octets (8 lanes) share one corner addr; each lane dwordx2 =
// 4 contiguous bf16 channels (aligned 64B line per octet). Descriptors
// (4 corner ptrs + 4 wgts) per-lane regs, recomputed every 4 chunks.
// ---------------------------------------------------------------------------
__global__ __launch_bounds__(256) void k_deform4(const ushort* __restrict__ xT,
                                                 const float* __restrict__ P,
                                                 const ushort* __restrict__ w2F,
                                                 float* __restrict__ out) {
    int bid = blockIdx.x;
    int L = (bid & 7) * 128 + (bid >> 3);
    int cs   = L & 1;
    int px0  = ((L >> 1) & 1) * 32;
    int h    = (L >> 2) & 63;
    int b    = L >> 8;
    int tid = threadIdx.x;
    int lane = tid & 63;
    int wv   = tid >> 6;
    int l16  = lane & 15;
    int lq   = lane >> 4;
    int oct  = lane >> 3;     // px within wave's octet group
    int cl   = lane & 7;      // channel slot: local ch = cl*4

    __shared__ ushort b_lds[2][4][2][16][8];   // [buf][kg][nt][px16][j] 4KB

    int px_loc = wv * 8 + oct;        // 0..31
    int pxg = px0 + px_loc;

    const char* xTb = (const char*)(xT + (size_t)b * CCH * HWSZ) + cs * 256 + cl * 8;
    const bf16x8* w2v = (const bf16x8*)w2F;

    unsigned int* wdstA = (unsigned int*)&b_lds[0][cl >> 1][px_loc >> 4][px_loc & 15][(cl & 1) * 4];
    unsigned int* wdstB = (unsigned int*)&b_lds[1][cl >> 1][px_loc >> 4][px_loc & 15][(cl & 1) * 4];

    f32x4 acc[4][2];
#pragma unroll
    for (int mf = 0; mf < 4; ++mf)
#pragma unroll
        for (int nf = 0; nf < 2; ++nf) acc[mf][nf] = (f32x4){0.f, 0.f, 0.f, 0.f};

    float wgt[4];
    const char* aptr[4];
    const float* Pb = P + (size_t)b * 27 * HWSZ + h * WW + pxg;

    auto make_desc = [&](int k) {
        float offy = Pb[(size_t)(2 * k) * HWSZ];
        float offx = Pb[(size_t)(2 * k + 1) * HWSZ];
        float m    = Pb[(size_t)(18 + k) * HWSZ];
        float sy = offy + (float)(h + k / 3 - 1);
        float sx = offx + (float)(pxg + k % 3 - 1);
        float y0f = floorf(sy), x0f = floorf(sx);
        float ty = sy - y0f, tx = sx - x0f;
        int y0 = (int)y0f, x0 = (int)x0f;
#pragma unroll
        for (int dy = 0; dy < 2; ++dy) {
#pragma unroll
            for (int dx = 0; dx < 2; ++dx) {
                int yi = y0 + dy, xi = x0 + dx;
                bool ok = (yi >= 0 && yi < HH && xi >= 0 && xi < WW);
                float wg = (dy ? ty : 1.0f - ty) * (dx ? tx : 1.0f - tx) * m;
                wgt[dy * 2 + dx]  = ok ? wg : 0.0f;
                aptr[dy * 2 + dx] = xTb + (size_t)(ok ? (yi * WW + xi) : 0) * 512;
            }
        }
    };

    auto combine_write = [&](uint2 g0, uint2 g1, uint2 g2, uint2 g3, unsigned int* wd) {
        float vx0 = wgt[0] * blo(g0.x) + wgt[1] * blo(g1.x) + wgt[2] * blo(g2.x) + wgt[3] * blo(g3.x);
        float vx1 = wgt[0] * bhi(g0.x) + wgt[1] * bhi(g1.x) + wgt[2] * bhi(g2.x) + wgt[3] * bhi(g3.x);
        float vy0 = wgt[0] * blo(g0.y) + wgt[1] * blo(g1.y) + wgt[2] * blo(g2.y) + wgt[3] * blo(g3.y);
        float vy1 = wgt[0] * bhi(g0.y) + wgt[1] * bhi(g1.y) + wgt[2] * bhi(g2.y) + wgt[3] * bhi(g3.y);
        wd[0] = bpack(vx0, vx1);
        wd[1] = bpack(vy0, vy1);
    };

    make_desc(0);
    // prologue: stage chunk 0 into buf A
    {
        uint2 g0 = *(const uint2*)(aptr[0]);
        uint2 g1 = *(const uint2*)(aptr[1]);
        uint2 g2 = *(const uint2*)(aptr[2]);
        uint2 g3 = *(const uint2*)(aptr[3]);
        combine_write(g0, g1, g2, g3, wdstA);
    }
    bf16x8 aCur[4];
    {
        int row = cs * 16 + lq;           // t=0: k=0, cgl=0
#pragma unroll
        for (int mf = 0; mf < 4; ++mf)
            aCur[mf] = w2v[(size_t)row * 256 + wv * 64 + mf * 16 + l16];
    }
    __syncthreads();

#pragma unroll 2
    for (int t = 0; t < 36; ++t) {
        int cur = t & 1;
        bool pf = (t < 35);
        bf16x8 aNxt[4];
        uint2 g0, g1, g2, g3;
        if (pf) {
            int tn = t + 1;
            int row = (tn >> 2) * 32 + cs * 16 + (tn & 3) * 4 + lq;
#pragma unroll
            for (int mf = 0; mf < 4; ++mf)
                aNxt[mf] = w2v[(size_t)row * 256 + wv * 64 + mf * 16 + l16];
            if ((tn & 3) == 0) make_desc(tn >> 2);
            int co = (tn & 3) * 64;
            g0 = *(const uint2*)(aptr[0] + co);
            g1 = *(const uint2*)(aptr[1] + co);
            g2 = *(const uint2*)(aptr[2] + co);
            g3 = *(const uint2*)(aptr[3] + co);
        }
        bf16x8 b0 = *(const bf16x8*)&b_lds[cur][lq][0][l16][0];
        bf16x8 b1 = *(const bf16x8*)&b_lds[cur][lq][1][l16][0];
#pragma unroll
        for (int mf = 0; mf < 4; ++mf) {
            acc[mf][0] = __builtin_amdgcn_mfma_f32_16x16x32_bf16(aCur[mf], b0, acc[mf][0], 0, 0, 0);
            acc[mf][1] = __builtin_amdgcn_mfma_f32_16x16x32_bf16(aCur[mf], b1, acc[mf][1], 0, 0, 0);
        }
        if (pf) {
            combine_write(g0, g1, g2, g3, cur ? wdstA : wdstB);
#pragma unroll
            for (int mf = 0; mf < 4; ++mf) aCur[mf] = aNxt[mf];
        }
        __syncthreads();
    }

    // epilogue: atomic accumulate (out prefilled with bias)
#pragma unroll
    for (int mf = 0; mf < 4; ++mf) {
#pragma unroll
        for (int nf = 0; nf < 2; ++nf) {
#pragma unroll
            for (int r = 0; r < 4; ++r) {
                int o = wv * 64 + mf * 16 + lq * 4 + r;
                atomicAdd(&out[((size_t)b * OCH + o) * HWSZ + h * WW + px0 + nf * 16 + l16],
                          acc[mf][nf][r]);
            }
        }
    }
}

// ---------------------------------------------------------------------------
extern "C" void kernel_launch(void* const* d_in, const int* in_sizes, int n_in,
                              void* d_out, int out_size, void* d_ws, size_t ws_size,
                              hipStream_t stream) {
    const float* x     = (const float*)d_in[0];
    const float* w_off = (const float*)d_in[1];
    const float* b_off = (const float*)d_in[2];
    const float* w_def = (const float*)d_in[3];
    const float* b_def = (const float*)d_in[4];
    float* out = (float*)d_out;

    float*  P   = (float*)d_ws;                            // 442368 f32
    ushort* w1F = (ushort*)(P + (size_t)BB * 27 * HWSZ);   // 73728 bf16
    ushort* w2F = w1F + 73728;                             // 589824 bf16
    ushort* xT  = w2F + 589824;                            // 4.19M bf16 (8.4MB)

    hipMemsetAsync(P, 0, (size_t)BB * 27 * HWSZ * sizeof(float), stream);
    hipLaunchKernelGGL(k_xT, dim3(BB * HH), dim3(256), 0, stream, x, xT);
    hipLaunchKernelGGL(k_w1f, dim3(288), dim3(256), 0, stream, w_off, w1F);
    hipLaunchKernelGGL(k_w2f, dim3(2304), dim3(256), 0, stream, w_def, w2F);
    hipLaunchKernelGGL(k_pred2, dim3(1024), dim3(256), 0, stream, x, w1F, P);
    hipLaunchKernelGGL(k_pfin, dim3(1728), dim3(256), 0, stream, P, b_off);
    hipLaunchKernelGGL(k_ofill, dim3(4096), dim3(256), 0, stream, out, b_def);
    hipLaunchKernelGGL(k_deform4, dim3(1024), dim3(256), 0, stream, xT, P, w2F, out);
}

// Round 6
// 98.792 us; speedup vs baseline: 1.7220x; 1.1561x over previous
//
#include <hip/hip_runtime.h>

#define BB 4
#define CCH 256
#define OCH 256
#define HH 64
#define WW 64
#define HWSZ 4096

typedef __bf16 bf16_t;
typedef bf16_t bf16x8 __attribute__((ext_vector_type(8)));
typedef float f32x4 __attribute__((ext_vector_type(4)));

__device__ __forceinline__ unsigned int bpack(float a, float b) {
    unsigned int ua = __float_as_uint(a);
    ua = (ua + 0x7FFFu + ((ua >> 16) & 1u)) >> 16;
    unsigned int ub = __float_as_uint(b);
    ub = (ub + 0x7FFFu + ((ub >> 16) & 1u)) >> 16;
    return ua | (ub << 16);
}
__device__ __forceinline__ float blo(unsigned int u) { return __uint_as_float(u << 16); }
__device__ __forceinline__ float bhi(unsigned int u) { return __uint_as_float(u & 0xFFFF0000u); }

// ---------------------------------------------------------------------------
// Kernel 0: transpose x [B][C][H][W] f32 -> xT [B][H][W][C] bf16
// ---------------------------------------------------------------------------
__global__ __launch_bounds__(256) void k_xT(const float* __restrict__ x,
                                            ushort* __restrict__ xT) {
    int b = blockIdx.x >> 6;
    int h = blockIdx.x & 63;
    int tid = threadIdx.x;
    int wv = tid >> 6;
    int lane = tid & 63;

    __shared__ unsigned int buf[64][130];

    const float* xp = x + ((size_t)b * CCH + wv * 64) * HWSZ + h * WW + lane;
#pragma unroll 8
    for (int i = 0; i < 32; ++i) {
        float a = xp[(size_t)(2 * i) * HWSZ];
        float c = xp[(size_t)(2 * i + 1) * HWSZ];
        buf[lane][wv * 32 + i] = bpack(a, c);
    }
    __syncthreads();

    ushort* dst = xT + ((size_t)(b * 64 + h) * 64) * 256;
#pragma unroll
    for (int r = 0; r < 16; ++r) {
        int idx = tid + r * 256;
        int w = idx >> 6;
        int q = idx & 63;
        uint2 v = *(const uint2*)&buf[w][2 * q];
        *(uint2*)(dst + (size_t)w * 256 + q * 4) = v;
    }
}

// ---------------------------------------------------------------------------
// Kernel prep (merged): w1F repack | w2F repack | P zero | out bias-prefill
//   w1F: [9 k][32 cSub][32 o][8 j] bf16 (o>=27 zero)
//   w2F: [9 k][32 cg][256 o][8 j]  bf16
// ---------------------------------------------------------------------------
__global__ void k_prep(const float* __restrict__ w_off, const float* __restrict__ w_def,
                       const float* __restrict__ b_def,
                       ushort* __restrict__ w1F, ushort* __restrict__ w2F,
                       float* __restrict__ P, float* __restrict__ out) {
    int i = blockIdx.x * blockDim.x + threadIdx.x;
    if (i < 73728) {
        int j = i & 7;
        int o = (i >> 3) & 31;
        int cSub = (i >> 8) & 31;
        int k = i >> 13;
        float v = 0.0f;
        if (o < 27) v = w_off[((size_t)o * CCH + cSub * 8 + j) * 9 + k];
        unsigned int u = __float_as_uint(v);
        u = (u + 0x7FFFu + ((u >> 16) & 1u)) >> 16;
        w1F[i] = (ushort)u;
        return;
    }
    i -= 73728;
    if (i < 589824) {
        int j = i & 7;
        int o = (i >> 3) & 255;
        int cg = (i >> 11) & 31;
        int k = i >> 16;
        float v = w_def[(size_t)o * 2304 + (cg * 8 + j) * 9 + k];
        unsigned int u = __float_as_uint(v);
        u = (u + 0x7FFFu + ((u >> 16) & 1u)) >> 16;
        w2F[i] = (ushort)u;
        return;
    }
    i -= 589824;
    if (i < 110592) {                       // P zero (float4)
        ((float4*)P)[i] = make_float4(0.f, 0.f, 0.f, 0.f);
        return;
    }
    i -= 110592;
    if (i < 1048576) {                      // out = bias (float4)
        float v = b_def[(i >> 10) & 255];
        ((float4*)out)[i] = make_float4(v, v, v, v);
    }
}

// ---------------------------------------------------------------------------
// Kernel 2: pred conv via MFMA, B staged densely from xT. Atomic K-split x4.
// grid = 1024, XCD-swizzled.
// ---------------------------------------------------------------------------
__global__ __launch_bounds__(256) void k_pred3(const ushort* __restrict__ xT,
                                               const ushort* __restrict__ w1F,
                                               float* __restrict__ P) {
    int bid = blockIdx.x;
    int L = (bid & 7) * 128 + (bid >> 3);
    int g = L & 3;
    int h = (L >> 2) & 63;
    int b = L >> 8;
    int tid = threadIdx.x;
    int spx  = tid & 63;
    int sgrp = tid >> 6;
    int lane = tid & 63;
    int wv   = tid >> 6;
    int l16  = lane & 15;
    int lq   = lane >> 4;

    __shared__ ushort b_lds[2][4][4][16][8];

    const ushort* xTb = xT + (size_t)b * HWSZ * 256;
    const bf16x8* w1v = (const bf16x8*)w1F;

    f32x4 acc[2];
    acc[0] = (f32x4){0.f, 0.f, 0.f, 0.f};
    acc[1] = (f32x4){0.f, 0.f, 0.f, 0.f};

    auto stage = [&](int t, int buf) {
        int cg = 2 * g + (t >= 9);
        int k = t - (t >= 9 ? 9 : 0);
        int y   = h + k / 3 - 1;
        int pxs = spx + k % 3 - 1;
        bool ok = (y >= 0 && y < HH && pxs >= 0 && pxs < WW);
        uint4 v = make_uint4(0u, 0u, 0u, 0u);
        if (ok) v = *(const uint4*)(xTb + (size_t)(y * WW + pxs) * 256 + cg * 32 + sgrp * 8);
        *(uint4*)&b_lds[buf][sgrp][spx >> 4][spx & 15][0] = v;
    };

    stage(0, 0);
    __syncthreads();

    for (int t = 0; t < 18; ++t) {
        int cur = t & 1;
        int cg = 2 * g + (t >= 9);
        int k  = t - (t >= 9 ? 9 : 0);
        int row = k * 32 + cg * 4 + lq;
        bf16x8 a0 = w1v[(size_t)row * 32 + 0 * 16 + l16];
        bf16x8 a1 = w1v[(size_t)row * 32 + 1 * 16 + l16];
        if (t < 17) stage(t + 1, cur ^ 1);
        bf16x8 bfrag = *(const bf16x8*)&b_lds[cur][lq][wv][l16][0];
        acc[0] = __builtin_amdgcn_mfma_f32_16x16x32_bf16(a0, bfrag, acc[0], 0, 0, 0);
        acc[1] = __builtin_amdgcn_mfma_f32_16x16x32_bf16(a1, bfrag, acc[1], 0, 0, 0);
        __syncthreads();
    }

#pragma unroll
    for (int mf = 0; mf < 2; ++mf) {
#pragma unroll
        for (int r = 0; r < 4; ++r) {
            int o = mf * 16 + lq * 4 + r;
            if (o < 27) {
                atomicAdd(&P[((size_t)b * 27 + o) * HWSZ + h * WW + wv * 16 + l16],
                          acc[mf][r]);
            }
        }
    }
}

// ---------------------------------------------------------------------------
// Kernel 3: deformable sampling + bf16 MFMA GEMM. 64-ch chunks, 1-chunk-deep
// gather pipeline, XOR-swizzled LDS staging. grid = 1024, XCD-swizzled.
// Chunk t (0..17): k = t>>1, c64 = t&1 -> channels cs*128 + c64*64 + [0,64).
// Bias+sigmoid folded into make_desc (reads raw P + b_off).
// ---------------------------------------------------------------------------
__global__ __launch_bounds__(256) void k_deform5(const ushort* __restrict__ xT,
                                                 const float* __restrict__ P,
                                                 const float* __restrict__ b_off,
                                                 const ushort* __restrict__ w2F,
                                                 float* __restrict__ out) {
    int bid = blockIdx.x;
    int L = (bid & 7) * 128 + (bid >> 3);
    int cs   = L & 1;
    int px0  = ((L >> 1) & 1) * 32;
    int h    = (L >> 2) & 63;
    int b    = L >> 8;
    int tid = threadIdx.x;
    int lane = tid & 63;
    int wv   = tid >> 6;
    int l16  = lane & 15;
    int lq   = lane >> 4;
    int oct  = lane >> 3;
    int cl   = lane & 7;
    int px_loc = wv * 8 + oct;            // 0..31
    int pxg = px0 + px_loc;

    __shared__ ushort b_lds[2][8][2][16][8];   // [buf][kg][nt][p^kg][j]  8KB

    const char* xTc = (const char*)xT + (size_t)b * HWSZ * 512 + cs * 256 + cl * 16;
    const bf16x8* w2b = (const bf16x8*)w2F + ((size_t)(cs * 16 + lq)) * 256 + wv * 64 + l16;

    uint4* wdst[2];
    wdst[0] = (uint4*)&b_lds[0][cl][px_loc >> 4][(px_loc & 15) ^ cl][0];
    wdst[1] = (uint4*)&b_lds[1][cl][px_loc >> 4][(px_loc & 15) ^ cl][0];

    f32x4 acc[4][2];
#pragma unroll
    for (int mf = 0; mf < 4; ++mf)
#pragma unroll
        for (int nf = 0; nf < 2; ++nf) acc[mf][nf] = (f32x4){0.f, 0.f, 0.f, 0.f};

    float wgt[4];
    const char* aptr[4];
    const float* Pb = P + (size_t)b * 27 * HWSZ + h * WW + pxg;

    auto make_desc = [&](int k) {
        float offy = Pb[(size_t)(2 * k) * HWSZ] + b_off[2 * k];
        float offx = Pb[(size_t)(2 * k + 1) * HWSZ] + b_off[2 * k + 1];
        float mr   = Pb[(size_t)(18 + k) * HWSZ] + b_off[18 + k];
        float m = 1.0f / (1.0f + expf(-mr));
        float sy = offy + (float)(h + k / 3 - 1);
        float sx = offx + (float)(pxg + k % 3 - 1);
        float y0f = floorf(sy), x0f = floorf(sx);
        float ty = sy - y0f, tx = sx - x0f;
        int y0 = (int)y0f, x0 = (int)x0f;
#pragma unroll
        for (int dy = 0; dy < 2; ++dy) {
#pragma unroll
            for (int dx = 0; dx < 2; ++dx) {
                int yi = y0 + dy, xi = x0 + dx;
                bool ok = (yi >= 0 && yi < HH && xi >= 0 && xi < WW);
                float wg = (dy ? ty : 1.0f - ty) * (dx ? tx : 1.0f - tx) * m;
                wgt[dy * 2 + dx]  = ok ? wg : 0.0f;
                aptr[dy * 2 + dx] = xTc + (size_t)(ok ? (yi * WW + xi) : 0) * 512;
            }
        }
    };

    uint4 gb[4];
    auto combine = [&]() -> uint4 {
        uint4 r;
        {
            float lo = wgt[0]*blo(gb[0].x) + wgt[1]*blo(gb[1].x) + wgt[2]*blo(gb[2].x) + wgt[3]*blo(gb[3].x);
            float hi = wgt[0]*bhi(gb[0].x) + wgt[1]*bhi(gb[1].x) + wgt[2]*bhi(gb[2].x) + wgt[3]*bhi(gb[3].x);
            r.x = bpack(lo, hi);
        }
        {
            float lo = wgt[0]*blo(gb[0].y) + wgt[1]*blo(gb[1].y) + wgt[2]*blo(gb[2].y) + wgt[3]*blo(gb[3].y);
            float hi = wgt[0]*bhi(gb[0].y) + wgt[1]*bhi(gb[1].y) + wgt[2]*bhi(gb[2].y) + wgt[3]*bhi(gb[3].y);
            r.y = bpack(lo, hi);
        }
        {
            float lo = wgt[0]*blo(gb[0].z) + wgt[1]*blo(gb[1].z) + wgt[2]*blo(gb[2].z) + wgt[3]*blo(gb[3].z);
            float hi = wgt[0]*bhi(gb[0].z) + wgt[1]*bhi(gb[1].z) + wgt[2]*bhi(gb[2].z) + wgt[3]*bhi(gb[3].z);
            r.z = bpack(lo, hi);
        }
        {
            float lo = wgt[0]*blo(gb[0].w) + wgt[1]*blo(gb[1].w) + wgt[2]*blo(gb[2].w) + wgt[3]*blo(gb[3].w);
            float hi = wgt[0]*bhi(gb[0].w) + wgt[1]*bhi(gb[1].w) + wgt[2]*bhi(gb[2].w) + wgt[3]*bhi(gb[3].w);
            r.w = bpack(lo, hi);
        }
        return r;
    };

    bf16x8 aCur[4][2], aNxt[4][2];
    auto loadA = [&](int t, bf16x8 dst[4][2]) {
        size_t base = ((size_t)((t >> 1) * 32 + (t & 1) * 8)) * 256;
#pragma unroll
        for (int gg = 0; gg < 2; ++gg)
#pragma unroll
            for (int mf = 0; mf < 4; ++mf)
                dst[mf][gg] = w2b[base + (size_t)gg * 4 * 256 + mf * 16];
    };

    // prologue: chunk 0
    make_desc(0);
#pragma unroll
    for (int c = 0; c < 4; ++c) gb[c] = *(const uint4*)(aptr[c]);
    loadA(0, aCur);
    *wdst[0] = combine();
    __syncthreads();

#pragma unroll 2
    for (int t = 0; t < 18; ++t) {
        int cur = t & 1;
        bool pf = (t < 17);
        if (pf) {
            int tf = t + 1;
            if ((tf & 1) == 0) make_desc(tf >> 1);
            int off = (tf & 1) * 128;
#pragma unroll
            for (int c = 0; c < 4; ++c) gb[c] = *(const uint4*)(aptr[c] + off);
            loadA(tf, aNxt);
        }
        bf16x8 bfr[2][2];
#pragma unroll
        for (int gg = 0; gg < 2; ++gg) {
            int kg = gg * 4 + lq;
#pragma unroll
            for (int nt = 0; nt < 2; ++nt)
                bfr[gg][nt] = *(const bf16x8*)&b_lds[cur][kg][nt][l16 ^ kg][0];
        }
#pragma unroll
        for (int gg = 0; gg < 2; ++gg)
#pragma unroll
            for (int mf = 0; mf < 4; ++mf) {
                acc[mf][0] = __builtin_amdgcn_mfma_f32_16x16x32_bf16(aCur[mf][gg], bfr[gg][0], acc[mf][0], 0, 0, 0);
                acc[mf][1] = __builtin_amdgcn_mfma_f32_16x16x32_bf16(aCur[mf][gg], bfr[gg][1], acc[mf][1], 0, 0, 0);
            }
        if (pf) {
            *wdst[cur ^ 1] = combine();
        }
        __syncthreads();
        if (pf) {
#pragma unroll
            for (int gg = 0; gg < 2; ++gg)
#pragma unroll
                for (int mf = 0; mf < 4; ++mf) aCur[mf][gg] = aNxt[mf][gg];
        }
    }

    // epilogue: atomic accumulate (out prefilled with bias)
#pragma unroll
    for (int mf = 0; mf < 4; ++mf) {
#pragma unroll
        for (int nf = 0; nf < 2; ++nf) {
#pragma unroll
            for (int r = 0; r < 4; ++r) {
                int o = wv * 64 + mf * 16 + lq * 4 + r;
                atomicAdd(&out[((size_t)b * OCH + o) * HWSZ + h * WW + px0 + nf * 16 + l16],
                          acc[mf][nf][r]);
            }
        }
    }
}

// ---------------------------------------------------------------------------
extern "C" void kernel_launch(void* const* d_in, const int* in_sizes, int n_in,
                              void* d_out, int out_size, void* d_ws, size_t ws_size,
                              hipStream_t stream) {
    const float* x     = (const float*)d_in[0];
    const float* w_off = (const float*)d_in[1];
    const float* b_off = (const float*)d_in[2];
    const float* w_def = (const float*)d_in[3];
    const float* b_def = (const float*)d_in[4];
    float* out = (float*)d_out;

    float*  P   = (float*)d_ws;                            // 442368 f32
    ushort* w1F = (ushort*)(P + (size_t)BB * 27 * HWSZ);   // 73728 bf16
    ushort* w2F = w1F + 73728;                             // 589824 bf16
    ushort* xT  = w2F + 589824;                            // 4.19M bf16

    hipLaunchKernelGGL(k_prep, dim3(7120), dim3(256), 0, stream,
                       w_off, w_def, b_def, w1F, w2F, P, out);
    hipLaunchKernelGGL(k_xT, dim3(BB * HH), dim3(256), 0, stream, x, xT);
    hipLaunchKernelGGL(k_pred3, dim3(1024), dim3(256), 0, stream, xT, w1F, P);
    hipLaunchKernelGGL(k_deform5, dim3(1024), dim3(256), 0, stream, xT, P, b_off, w2F, out);
}